// Round 5
// baseline (152.464 us; speedup 1.0000x reference)
//
#include <hip/hip_runtime.h>

#define N 192
#define NSLOT 1338            // 6 dx-blocks * 223 valid c each
#define G5ROW (NSLOT * 32)    // 42816 ushorts per y-row
#define YSLICE 48             // y rows per slice (4 slices)

typedef __attribute__((ext_vector_type(8))) short short8;   // 8 bf16
typedef __attribute__((ext_vector_type(4))) float f32x4;

static __device__ __forceinline__ unsigned short f2bf(float x) {
    uint32_t u = __builtin_bit_cast(uint32_t, x);
    u += 0x7FFFu + ((u >> 16) & 1u);          // RNE (inputs finite)
    return (unsigned short)(u >> 16);
}

// ---------------------------------------------------------------------------
// prep: Abf[r][c] (384x384 uint32 = packed (bf16 Ar, bf16 -Ai), pad rows/cols
// zero) and Wt[dx][dy] (192x192 uint32 = packed (bf16 Wr, bf16 Wi)).
// Kfac = cos(atan2(rho,z)) == z/R ; amp = Kfac/R = z/(r2+z^2).
// ---------------------------------------------------------------------------
__global__ __launch_bounds__(256) void prep_kernel(const float* __restrict__ fr,
                                                   const float* __restrict__ fi,
                                                   const float* __restrict__ zp,
                                                   uint32_t* __restrict__ Abf,
                                                   uint32_t* __restrict__ Wt) {
    int idx = blockIdx.x * 256 + threadIdx.x;
    float z = zp[0];
    if (idx < 384 * 384) {
        int r = idx / 384, c = idx - r * 384;
        uint32_t pack = 0u;
        if (r < 383 && c < 383) {
            const float X0 = 191.00005f;      // 0.5*(2*192 + 1e-4) - 1
            float xr = (float)r - X0;
            float yc = (float)c - X0;
            float r2 = xr * xr + yc * yc;
            float R2 = r2 + z * z;
            float R  = sqrtf(R2);
            float amp = z / R2;
            float ph = 12.566371f * R;        // 2*pi/0.5
            float sv, cv;
            sincosf(ph, &sv, &cv);
            pack = (uint32_t)f2bf(amp * cv) | ((uint32_t)f2bf(-amp * sv) << 16);
        }
        Abf[idx] = pack;
    }
    if (idx < N * N) {
        int dy = idx / N, dx = idx - dy * N;
        Wt[dx * N + dy] = (uint32_t)f2bf(fr[idx]) | ((uint32_t)f2bf(fi[idx]) << 16);
    }
}

// ---------------------------------------------------------------------------
// stage 1: per (c, dx-block) GEMM slab via mfma_f32_16x16x32_bf16.
//   G[c][y][dx] = sum_dy Ar[y+dy][c]*Wr[dy][dx] - Ai[y+dy][c]*Wi[dy][dx]
// K = 384 (dy x {re,im} interleaved). A-frag from Hankel reads of one A row
// (A symmetric: row c == col c) held in LDS as duplicated 8B-aligned pairs.
// B-frags (2 dx-tiles x 12 ksteps) in registers, loaded once from L2.
// Block: 192 thr = 3 waves, wave w owns y-tile w (16 rows), 48 y per slice.
// G5 rows are SLICE-LOCAL (0..47).
// ---------------------------------------------------------------------------
__global__ __launch_bounds__(192) void s1_kernel(const uint32_t* __restrict__ Abf,
                                                 const uint32_t* __restrict__ Wt,
                                                 unsigned short* __restrict__ G5,
                                                 int yoff) {
    __shared__ uint2 colAd[384];     // colAd[i] = (pair[i], pair[i+1]) : 3 KB

    const int tid = threadIdx.x;
    const int l   = tid & 63;
    const int w   = tid >> 6;        // wave -> y-tile
    const int bid = blockIdx.x;
    const int db  = bid / 223;
    const int ci  = bid - db * 223;
    const int c   = db * 32 + ci;
    const int dx0 = db * 32;
    const int m   = l & 15;
    const int kg  = l >> 4;

    // B fragments: 2 dx-tiles x 12 ksteps, registers for the whole kernel.
    uint4 bfr[2][12];
    #pragma unroll
    for (int t = 0; t < 2; ++t) {
        int dx = dx0 + t * 16 + m;
        #pragma unroll
        for (int ks = 0; ks < 12; ++ks)
            bfr[t][ks] = *(const uint4*)(Wt + dx * N + ks * 16 + kg * 4);
    }

    // stage duplicated column-c pairs into LDS (row c of Abf, A symmetric)
    for (int i = tid; i < 383; i += 192) {
        uint32_t v0 = Abf[c * 384 + i];
        uint32_t v1 = (i < 382) ? Abf[c * 384 + i + 1] : 0u;
        colAd[i] = make_uint2(v0, v1);
    }
    __syncthreads();

    f32x4 acc0 = {0.f, 0.f, 0.f, 0.f};
    f32x4 acc1 = {0.f, 0.f, 0.f, 0.f};
    const int srow = yoff + w * 16 + m;

    #pragma unroll
    for (int ks = 0; ks < 12; ++ks) {
        int s = srow + ks * 16 + kg * 4;          // <= 379
        uint2 a0 = colAd[s];                      // pairs s, s+1
        uint2 a1 = colAd[s + 2];                  // pairs s+2, s+3
        union { uint32_t u[4]; short8 v; } af;
        af.u[0] = a0.x; af.u[1] = a0.y; af.u[2] = a1.x; af.u[3] = a1.y;
        union { uint4 q; short8 v; } b0, b1;
        b0.q = bfr[0][ks]; b1.q = bfr[1][ks];
        acc0 = __builtin_amdgcn_mfma_f32_16x16x32_bf16(af.v, b0.v, acc0, 0, 0, 0);
        acc1 = __builtin_amdgcn_mfma_f32_16x16x32_bf16(af.v, b1.v, acc1, 0, 0, 0);
    }

    // C/D layout: col = lane&15, row = (lane>>4)*4 + reg   [m89]
    const int y_loc = w * 16 + kg * 4;            // slice-local y
    #pragma unroll
    for (int r = 0; r < 4; ++r) {
        size_t row = (size_t)(y_loc + r) * G5ROW + (size_t)bid * 32;
        G5[row + m]      = f2bf(acc0[r]);
        G5[row + 16 + m] = f2bf(acc1[r]);
    }
}

// ---------------------------------------------------------------------------
// stage 2: out[y][x] = sum_dx G[x+dx][y][dx], flip fused into the store.
// Block = 32 x-values x 2 y-rows (64 thr). Stages the 6 db-windows
// (63 slots x 32 each) for both y rows into LDS, then 192-tap band sum.
// G5 is indexed with SLICE-LOCAL rows; output with global y.  [round-4 fix]
// ---------------------------------------------------------------------------
#define S2PITCH (6 * 2016 + 16)     // ushorts per y row in LDS (pad vs 2-row alias)

__global__ __launch_bounds__(64) void s2_kernel(const unsigned short* __restrict__ G5,
                                                float* __restrict__ out,
                                                int yoff) {
    __shared__ __align__(16) unsigned short lds[2 * S2PITCH];   // 48448 B

    const int tid  = threadIdx.x;
    const int x0   = blockIdx.x * 32;
    const int yloc0 = blockIdx.y * 2;            // slice-local row for G5

    // stage: per (yl, db): 63 slots * 32 = 2016 contiguous ushorts = 252 uint4
    for (int u = tid; u < 3024; u += 64) {
        int yl  = u / 1512;
        int rem = u - yl * 1512;
        int db  = rem / 252;
        int t   = rem - db * 252;
        const uint4* src = (const uint4*)(G5 + (size_t)(yloc0 + yl) * G5ROW
                                             + (size_t)(db * 223 + x0) * 32) + t;
        ((uint4*)lds)[yl * (S2PITCH / 8) + db * 252 + t] = *src;
    }
    __syncthreads();

    const int x_l = tid & 31;
    const int yl  = tid >> 5;
    const int base = yl * S2PITCH + x_l * 32;
    float sum = 0.f;
    #pragma unroll
    for (int db = 0; db < 6; ++db) {
        int b2 = base + db * 2016;
        #pragma unroll
        for (int j = 0; j < 32; ++j) {   // local slot = x_l + j, elem = j
            sum += __builtin_bit_cast(float, (uint32_t)lds[b2 + j * 33] << 16);
        }
    }
    int y = yoff + yloc0 + yl;                   // global y for output
    int x = x0 + x_l;
    out[(191 - y) * N + (191 - x)] = sum;
}

extern "C" void kernel_launch(void* const* d_in, const int* in_sizes, int n_in,
                              void* d_out, int out_size, void* d_ws, size_t ws_size,
                              hipStream_t stream) {
    const float* fr = (const float*)d_in[0];
    const float* fi = (const float*)d_in[1];
    const float* zp = (const float*)d_in[2];

    uint32_t* Abf = (uint32_t*)d_ws;                       // 384*384 u32 = 576 KB
    uint32_t* Wt  = Abf + 384 * 384;                       // 192*192 u32 = 144 KB
    unsigned short* G5 = (unsigned short*)(Wt + N * N);    // 48*42816 u16 = 4.11 MB
    // total ws: ~4.85 MB

    prep_kernel<<<(384 * 384 + 255) / 256, 256, 0, stream>>>(fr, fi, zp, Abf, Wt);
    for (int s = 0; s < 4; ++s) {
        int yoff = s * YSLICE;
        s1_kernel<<<NSLOT, 192, 0, stream>>>(Abf, Wt, G5, yoff);
        s2_kernel<<<dim3(6, 24), 64, 0, stream>>>(G5, (float*)d_out, yoff);
    }
}

// Round 6
// 56.616 us; speedup vs baseline: 2.6930x; 2.6930x over previous
//
#include <hip/hip_runtime.h>

#define N 192
#define NSLOT 1338            // 6 dx-blocks * 223 valid c each
#define G5ROW (NSLOT * 32)    // 42816 ushorts per global-y row
#define CCHUNK 8              // c columns per block (B-frag reuse)
#define NCHUNK 28             // ceil(223 / CCHUNK)

typedef __attribute__((ext_vector_type(8))) short short8;   // 8 bf16
typedef __attribute__((ext_vector_type(4))) float f32x4;

static __device__ __forceinline__ unsigned short f2bf(float x) {
    uint32_t u = __builtin_bit_cast(uint32_t, x);
    u += 0x7FFFu + ((u >> 16) & 1u);          // RNE (inputs finite)
    return (unsigned short)(u >> 16);
}

// ---------------------------------------------------------------------------
// prep: Abf[r][c] (384x384 uint32 = packed (bf16 Ar, bf16 -Ai), pad row/col
// 383 zero) and Wt[dx][dy] (192x192 uint32 = packed (bf16 Wr, bf16 Wi)).
// Kfac/R = cos(atan2(rho,z))/R = z/(r2+z^2).
// ---------------------------------------------------------------------------
__global__ __launch_bounds__(256) void prep_kernel(const float* __restrict__ fr,
                                                   const float* __restrict__ fi,
                                                   const float* __restrict__ zp,
                                                   uint32_t* __restrict__ Abf,
                                                   uint32_t* __restrict__ Wt) {
    int idx = blockIdx.x * 256 + threadIdx.x;
    float z = zp[0];
    if (idx < 384 * 384) {
        int r = idx / 384, c = idx - r * 384;
        uint32_t pack = 0u;
        if (r < 383 && c < 383) {
            const float X0 = 191.00005f;      // 0.5*(2*192 + 1e-4) - 1
            float xr = (float)r - X0;
            float yc = (float)c - X0;
            float r2 = xr * xr + yc * yc;
            float R2 = r2 + z * z;
            float R  = sqrtf(R2);
            float amp = z / R2;
            float ph = 12.566371f * R;        // 2*pi/0.5
            float sv, cv;
            sincosf(ph, &sv, &cv);
            pack = (uint32_t)f2bf(amp * cv) | ((uint32_t)f2bf(-amp * sv) << 16);
        }
        Abf[idx] = pack;
    }
    if (idx < N * N) {
        int dy = idx / N, dx = idx - dy * N;
        Wt[dx * N + dy] = (uint32_t)f2bf(fr[idx]) | ((uint32_t)f2bf(fi[idx]) << 16);
    }
}

// ---------------------------------------------------------------------------
// stage 1: G[c][y][dx] = sum_dy Ar[y+dy][c]*Wr[dy][dx] - Ai[y+dy][c]*Wi[dy][dx]
// via mfma_f32_16x16x32_bf16, K=384 (dy x re/im interleaved).
// Block = (db, chunk of 8 c's, y-third of 64 rows), 4 waves = 4 y-tiles.
// B-frags (2 dx-tiles x 12 ksteps) loaded ONCE per block -> 8x traffic cut.
// A column (duplicated 8B pairs) double-buffered in LDS, 1 barrier per c.
// G5 rows are GLOBAL y (0..191).
// ---------------------------------------------------------------------------
__global__ __launch_bounds__(256) void s1_kernel(const uint32_t* __restrict__ Abf,
                                                 const uint32_t* __restrict__ Wt,
                                                 unsigned short* __restrict__ G5) {
    __shared__ uint2 colAd[2][384];           // 6 KB double buffer

    const int tid  = threadIdx.x;
    const int l    = tid & 63;
    const int w    = tid >> 6;                // wave -> y-tile within third
    const int db   = blockIdx.x / NCHUNK;
    const int ck   = blockIdx.x - db * NCHUNK;
    const int ci0  = ck * CCHUNK;
    const int dx0  = db * 32;
    const int yoff = blockIdx.y * 64;
    const int m    = l & 15;
    const int kg   = l >> 4;

    // B fragments: loaded once, live in registers for all 8 c's.
    uint4 bfr[2][12];
    #pragma unroll
    for (int t = 0; t < 2; ++t) {
        int dx = dx0 + t * 16 + m;
        #pragma unroll
        for (int ks = 0; ks < 12; ++ks)
            bfr[t][ks] = *(const uint4*)(Wt + dx * N + ks * 16 + kg * 4);
    }

    // stage first column (c0 <= 383; row 383 of Abf is zero padding)
    {
        int c0 = db * 32 + ci0;
        for (int i = tid; i < 383; i += 256) {
            uint32_t v0 = Abf[c0 * 384 + i];
            uint32_t v1 = (i < 382) ? Abf[c0 * 384 + i + 1] : 0u;
            colAd[0][i] = make_uint2(v0, v1);
        }
    }
    __syncthreads();

    for (int q = 0; q < CCHUNK; ++q) {
        const int ci  = ci0 + q;
        const int cur = q & 1;
        // prefetch next column into the other buffer (no hazard: other buf)
        if (q < CCHUNK - 1) {
            int cn = db * 32 + ci + 1;        // <= 383
            for (int i = tid; i < 383; i += 256) {
                uint32_t v0 = Abf[cn * 384 + i];
                uint32_t v1 = (i < 382) ? Abf[cn * 384 + i + 1] : 0u;
                colAd[cur ^ 1][i] = make_uint2(v0, v1);
            }
        }

        f32x4 acc0 = {0.f, 0.f, 0.f, 0.f};
        f32x4 acc1 = {0.f, 0.f, 0.f, 0.f};
        const int srow = yoff + w * 16 + m;
        #pragma unroll
        for (int ks = 0; ks < 12; ++ks) {
            int s = srow + ks * 16 + kg * 4;          // <= 379
            uint2 a0 = colAd[cur][s];                 // pairs s, s+1
            uint2 a1 = colAd[cur][s + 2];             // pairs s+2, s+3
            union { uint32_t u[4]; short8 v; } af;
            af.u[0] = a0.x; af.u[1] = a0.y; af.u[2] = a1.x; af.u[3] = a1.y;
            union { uint4 q4; short8 v; } b0, b1;
            b0.q4 = bfr[0][ks]; b1.q4 = bfr[1][ks];
            acc0 = __builtin_amdgcn_mfma_f32_16x16x32_bf16(af.v, b0.v, acc0, 0, 0, 0);
            acc1 = __builtin_amdgcn_mfma_f32_16x16x32_bf16(af.v, b1.v, acc1, 0, 0, 0);
        }

        if (ci < 223) {                       // guard chunk tail (ci==223 pad)
            const int slot  = db * 223 + ci;
            const int y_loc = yoff + w * 16 + kg * 4;     // global y
            #pragma unroll
            for (int r = 0; r < 4; ++r) {
                size_t row = (size_t)(y_loc + r) * G5ROW + (size_t)slot * 32;
                G5[row + m]      = f2bf(acc0[r]);
                G5[row + 16 + m] = f2bf(acc1[r]);
            }
        }
        __syncthreads();   // next iter reads the buffer staged this iter
    }
}

// ---------------------------------------------------------------------------
// stage 2: out[y][x] = sum_dx G[x+dx][y][dx], flip fused into the store.
// Block = 32 x-values x 2 y-rows (64 thr), grid (6 x-blocks, 96 y-pairs).
// ---------------------------------------------------------------------------
#define S2PITCH (6 * 2016 + 16)     // ushorts per y row in LDS

__global__ __launch_bounds__(64) void s2_kernel(const unsigned short* __restrict__ G5,
                                                float* __restrict__ out) {
    __shared__ __align__(16) unsigned short lds[2 * S2PITCH];   // 48448 B

    const int tid = threadIdx.x;
    const int x0  = blockIdx.x * 32;
    const int y0  = blockIdx.y * 2;           // global y

    // stage: per (yl, db): 63 slots * 32 = 2016 contiguous ushorts = 252 uint4
    for (int u = tid; u < 3024; u += 64) {
        int yl  = u / 1512;
        int rem = u - yl * 1512;
        int db  = rem / 252;
        int t   = rem - db * 252;
        const uint4* src = (const uint4*)(G5 + (size_t)(y0 + yl) * G5ROW
                                             + (size_t)(db * 223 + x0) * 32) + t;
        ((uint4*)lds)[yl * (S2PITCH / 8) + db * 252 + t] = *src;
    }
    __syncthreads();

    const int x_l = tid & 31;
    const int yl  = tid >> 5;
    const int base = yl * S2PITCH + x_l * 32;
    float sum = 0.f;
    #pragma unroll
    for (int db = 0; db < 6; ++db) {
        int b2 = base + db * 2016;
        #pragma unroll
        for (int j = 0; j < 32; ++j) {   // local slot = x_l + j, elem = j
            sum += __builtin_bit_cast(float, (uint32_t)lds[b2 + j * 33] << 16);
        }
    }
    int y = y0 + yl, x = x0 + x_l;
    out[(191 - y) * N + (191 - x)] = sum;
}

extern "C" void kernel_launch(void* const* d_in, const int* in_sizes, int n_in,
                              void* d_out, int out_size, void* d_ws, size_t ws_size,
                              hipStream_t stream) {
    const float* fr = (const float*)d_in[0];
    const float* fi = (const float*)d_in[1];
    const float* zp = (const float*)d_in[2];

    uint32_t* Abf = (uint32_t*)d_ws;                       // 384*384 u32 = 576 KB
    uint32_t* Wt  = Abf + 384 * 384;                       // 192*192 u32 = 144 KB
    unsigned short* G5 = (unsigned short*)(Wt + N * N);    // 192*42816 u16 = 16.4 MB
    // total ws ~17.2 MB (ws is >= 268 MB per harness fill size)

    prep_kernel<<<(384 * 384 + 255) / 256, 256, 0, stream>>>(fr, fi, zp, Abf, Wt);
    s1_kernel<<<dim3(6 * NCHUNK, 3), 256, 0, stream>>>(Abf, Wt, G5);
    s2_kernel<<<dim3(6, 96), 64, 0, stream>>>(G5, (float*)d_out);
}